// Round 1
// baseline (13284.288 us; speedup 1.0000x reference)
//
#include <hip/hip_runtime.h>

#define CCH 128   // channels
#define RROWS 16  // rows staged per block-iteration
#define VPAD 20   // vT leading-dim pad (float2-aligned, conflict-light)

// Generic "rows x (128x128 linear)" kernel.
//   v[row]  = srcA[idxA?idxA[row]:row]  (+ srcB[idxB?idxB[row]:row] if srcB)
//   y[row]  = act(v @ W^T + bias)            (act = relu if RELU)
//   OUT_MODE 0: out[row] = y
//   OUT_MODE 1: atomicAdd(out[idxO[row]], y)      (segment-sum)
//   OUT_MODE 2: out[row] = y + res[row]           (res may alias out)
// W is [out,in] row-major (torch Linear), y[c] = sum_k v[k]*W[c*128+k] + b[c].
template <bool RELU, int OUT_MODE>
__global__ __launch_bounds__(256, 2) void rowlin(
    const float* __restrict__ srcA, const int* __restrict__ idxA,
    const float* __restrict__ srcB, const int* __restrict__ idxB,
    const float* __restrict__ W, const float* __restrict__ bias,
    float* __restrict__ out, const int* __restrict__ idxO,
    const float* __restrict__ res, int nrows)
{
    // Wt[k][c] = W[c][k]; +4 pad so the transpose store isn't 32-way conflicted.
    __shared__ float Wt[CCH][CCH + 4];
    __shared__ float vT[CCH][VPAD];   // k-major staged rows

    const int t = threadIdx.x;

    for (int i = t; i < CCH * CCH; i += 256) {
        int c = i >> 7, k = i & 127;   // coalesced read of W, transposed store
        Wt[k][c] = W[i];
    }

    const int cq = t & 31;   // channel quad: channels 4cq..4cq+3
    const int rg = t >> 5;   // row group:   rows 2rg, 2rg+1
    const float4 b4 = ((const float4*)bias)[cq];

    const int niter = (nrows + RROWS - 1) / RROWS;
    for (int it = blockIdx.x; it < niter; it += gridDim.x) {
        const int rowbase = it * RROWS;

        __syncthreads();   // previous iter's compute reads of vT are done
        #pragma unroll
        for (int i = 0; i < 8; ++i) {
            int flat = (i << 8) + t;    // over (row 0..15, k 0..127)
            int r = flat >> 7;
            int k = flat & 127;
            int row = rowbase + r;
            float v = 0.f;
            if (row < nrows) {
                int ia = idxA ? idxA[row] : row;
                v = srcA[(size_t)ia * CCH + k];
                if (srcB) {
                    int ib = idxB ? idxB[row] : row;
                    v += srcB[(size_t)ib * CCH + k];
                }
            }
            vT[k][r] = v;
        }
        __syncthreads();

        float a00 = 0, a01 = 0, a02 = 0, a03 = 0;
        float a10 = 0, a11 = 0, a12 = 0, a13 = 0;
        #pragma unroll 8
        for (int k = 0; k < CCH; ++k) {
            const float4 w = *(const float4*)&Wt[k][cq << 2];
            const float2 v = *(const float2*)&vT[k][rg << 1];
            a00 = fmaf(w.x, v.x, a00);
            a01 = fmaf(w.y, v.x, a01);
            a02 = fmaf(w.z, v.x, a02);
            a03 = fmaf(w.w, v.x, a03);
            a10 = fmaf(w.x, v.y, a10);
            a11 = fmaf(w.y, v.y, a11);
            a12 = fmaf(w.z, v.y, a12);
            a13 = fmaf(w.w, v.y, a13);
        }

        #pragma unroll
        for (int rr = 0; rr < 2; ++rr) {
            int row = rowbase + (rg << 1) + rr;
            if (row >= nrows) continue;
            float4 y;
            if (rr == 0) { y.x = a00; y.y = a01; y.z = a02; y.w = a03; }
            else         { y.x = a10; y.y = a11; y.z = a12; y.w = a13; }
            y.x += b4.x; y.y += b4.y; y.z += b4.z; y.w += b4.w;
            if (RELU) {
                y.x = fmaxf(y.x, 0.f); y.y = fmaxf(y.y, 0.f);
                y.z = fmaxf(y.z, 0.f); y.w = fmaxf(y.w, 0.f);
            }
            if (OUT_MODE == 0) {
                ((float4*)(out + (size_t)row * CCH))[cq] = y;
            } else if (OUT_MODE == 2) {
                const float4 rv = ((const float4*)(res + (size_t)row * CCH))[cq];
                y.x += rv.x; y.y += rv.y; y.z += rv.z; y.w += rv.w;
                ((float4*)(out + (size_t)row * CCH))[cq] = y;
            } else {
                float* p = out + (size_t)idxO[row] * CCH + (cq << 2);
                unsafeAtomicAdd(p + 0, y.x);   // native global_atomic_add_f32
                unsafeAtomicAdd(p + 1, y.y);
                unsafeAtomicAdd(p + 2, y.z);
                unsafeAtomicAdd(p + 3, y.w);
            }
        }
    }
}

extern "C" void kernel_launch(void* const* d_in, const int* in_sizes, int n_in,
                              void* d_out, int out_size, void* d_ws, size_t ws_size,
                              hipStream_t stream)
{
    const float* x0     = (const float*)d_in[0];
    const float* x1     = (const float*)d_in[1];
    const float* x2     = (const float*)d_in[2];
    const int*   ei1    = (const int*)d_in[3];
    const int*   ei2    = (const int*)d_in[4];
    const int*   tri111 = (const int*)d_in[5];
    const int*   tri222 = (const int*)d_in[6];
    const int*   tri112 = (const int*)d_in[7];
    const int*   inv1   = (const int*)d_in[8];
    // d_in[9] = inv2 (unused by the reference)
    const float* inner_W = (const float*)d_in[10];
    const float* inner_b = (const float*)d_in[11];
    const float* l111_W  = (const float*)d_in[12];
    const float* l111_b  = (const float*)d_in[13];
    const float* l222_W  = (const float*)d_in[14];
    const float* l222_b  = (const float*)d_in[15];
    const float* l211_W  = (const float*)d_in[16];
    const float* l211_b  = (const float*)d_in[17];
    const float* m0a_W   = (const float*)d_in[18];
    const float* m0a_b   = (const float*)d_in[19];
    const float* m0b_W   = (const float*)d_in[20];
    const float* m0b_b   = (const float*)d_in[21];
    const float* m1a_W   = (const float*)d_in[22];
    const float* m1a_b   = (const float*)d_in[23];
    const float* m1b_W   = (const float*)d_in[24];
    const float* m1b_b   = (const float*)d_in[25];
    const float* m2a_W   = (const float*)d_in[26];
    const float* m2a_b   = (const float*)d_in[27];
    const float* m2b_W   = (const float*)d_in[28];
    const float* m2b_b   = (const float*)d_in[29];

    const int N0 = in_sizes[0] / CCH;
    const int E1 = in_sizes[1] / CCH;
    const int E2 = in_sizes[2] / CCH;
    const int T  = in_sizes[7] / 3;

    float* o0 = (float*)d_out;                 // doubles as a0 accumulator
    float* o1 = o0 + (size_t)N0 * CCH;         // doubles as a1 accumulator
    float* o2 = o1 + (size_t)E1 * CCH;         // doubles as a2 accumulator
    float* tmp = (float*)d_ws;                 // one E-sized segment/hidden buffer

    const int GRID = 512;  // 2 blocks/CU x 256 CUs
    const int BLK  = 256;
    const size_t rowBytes1 = (size_t)E1 * CCH * sizeof(float);
    const size_t rowBytes2 = (size_t)E2 * CCH * sizeof(float);

    // a0 region starts as zeros (ws/out are poisoned each call)
    hipMemsetAsync(o0, 0, (size_t)N0 * CCH * sizeof(float), stream);

    // aggr (0,1,1): a1 = inner(x0[s] + x0[e]); a0 += seg(inner(x1), s)
    rowlin<true, 0><<<GRID, BLK, 0, stream>>>(x0, ei1, x0, ei1 + E1,
                                              inner_W, inner_b, o1, nullptr, nullptr, E1);
    rowlin<true, 1><<<GRID, BLK, 0, stream>>>(x1, nullptr, nullptr, nullptr,
                                              inner_W, inner_b, o0, ei1, nullptr, E1);
    // aggr (0,2,2)
    rowlin<true, 0><<<GRID, BLK, 0, stream>>>(x0, ei2, x0, ei2 + E2,
                                              inner_W, inner_b, o2, nullptr, nullptr, E2);
    rowlin<true, 1><<<GRID, BLK, 0, stream>>>(x2, nullptr, nullptr, nullptr,
                                              inner_W, inner_b, o0, ei2, nullptr, E2);

    // aggr (1,1,1): a1 += l111(seg(inner(x1[t1]+x1[t2]), t0, E1))
    hipMemsetAsync(tmp, 0, rowBytes1, stream);
    rowlin<true, 1><<<GRID, BLK, 0, stream>>>(x1, tri111 + T, x1, tri111 + 2 * T,
                                              inner_W, inner_b, tmp, tri111, nullptr, T);
    rowlin<false, 2><<<GRID, BLK, 0, stream>>>(tmp, nullptr, nullptr, nullptr,
                                               l111_W, l111_b, o1, nullptr, o1, E1);

    // aggr (2,2,2): a2 += l222(seg(inner(x2[t1]+x2[t2]), t0, E2))
    hipMemsetAsync(tmp, 0, rowBytes2, stream);
    rowlin<true, 1><<<GRID, BLK, 0, stream>>>(x2, tri222 + T, x2, tri222 + 2 * T,
                                              inner_W, inner_b, tmp, tri222, nullptr, T);
    rowlin<false, 2><<<GRID, BLK, 0, stream>>>(tmp, nullptr, nullptr, nullptr,
                                               l222_W, l222_b, o2, nullptr, o2, E2);

    // aggr (1,1,2) part A: a2 += l211(seg(inner(x1[t0]+x1[t1]), t2, E2))
    hipMemsetAsync(tmp, 0, rowBytes2, stream);
    rowlin<true, 1><<<GRID, BLK, 0, stream>>>(x1, tri112, x1, tri112 + T,
                                              inner_W, inner_b, tmp, tri112 + 2 * T, nullptr, T);
    rowlin<false, 2><<<GRID, BLK, 0, stream>>>(tmp, nullptr, nullptr, nullptr,
                                               l211_W, l211_b, o2, nullptr, o2, E2);

    // aggr (1,1,2) part B: out_iji = seg(inner(x1[t1]+x2[t2]), t0, E1);
    //                      a1 += l211(out_iji + out_iji[inv1])
    hipMemsetAsync(tmp, 0, rowBytes1, stream);
    rowlin<true, 1><<<GRID, BLK, 0, stream>>>(x1, tri112 + T, x2, tri112 + 2 * T,
                                              inner_W, inner_b, tmp, tri112, nullptr, T);
    rowlin<false, 2><<<GRID, BLK, 0, stream>>>(tmp, nullptr, tmp, inv1,
                                               l211_W, l211_b, o1, nullptr, o1, E1);

    // Final MLPs: o = m_b(relu(m_a(x + a))) + x   (eps = 0)
    rowlin<true, 0><<<GRID, BLK, 0, stream>>>(x0, nullptr, o0, nullptr,
                                              m0a_W, m0a_b, tmp, nullptr, nullptr, N0);
    rowlin<false, 2><<<GRID, BLK, 0, stream>>>(tmp, nullptr, nullptr, nullptr,
                                               m0b_W, m0b_b, o0, nullptr, x0, N0);

    rowlin<true, 0><<<GRID, BLK, 0, stream>>>(x1, nullptr, o1, nullptr,
                                              m1a_W, m1a_b, tmp, nullptr, nullptr, E1);
    rowlin<false, 2><<<GRID, BLK, 0, stream>>>(tmp, nullptr, nullptr, nullptr,
                                               m1b_W, m1b_b, o1, nullptr, x1, E1);

    rowlin<true, 0><<<GRID, BLK, 0, stream>>>(x2, nullptr, o2, nullptr,
                                              m2a_W, m2a_b, tmp, nullptr, nullptr, E2);
    rowlin<false, 2><<<GRID, BLK, 0, stream>>>(tmp, nullptr, nullptr, nullptr,
                                               m2b_W, m2b_b, o2, nullptr, x2, E2);
}